// Round 2
// baseline (238.042 us; speedup 1.0000x reference)
//
#include <hip/hip_runtime.h>

#define B_N   8
#define S_LEN 2048
#define D_DIM 256

typedef __attribute__((ext_vector_type(4)))  float          f32x4;
typedef __attribute__((ext_vector_type(16))) float          f32x16;
typedef __attribute__((ext_vector_type(8)))  short          s16x8;
typedef __attribute__((ext_vector_type(8)))  __bf16         b16x8;
typedef __attribute__((ext_vector_type(8)))  unsigned short u16x8;

// ---- bf16 helpers (RNE) ----
__device__ __forceinline__ unsigned short f2bf(float f) {
    unsigned u = __builtin_bit_cast(unsigned, f);
    u += 0x7FFFu + ((u >> 16) & 1u);
    return (unsigned short)(u >> 16);
}
__device__ __forceinline__ u16x8 pack8(f32x4 a, f32x4 b) {
    u16x8 o;
#pragma unroll
    for (int u = 0; u < 4; ++u) { o[u] = f2bf(a[u]); o[u + 4] = f2bf(b[u]); }
    return o;
}
__device__ __forceinline__ f32x16 zero16() {
    f32x16 z;
#pragma unroll
    for (int i = 0; i < 16; ++i) z[i] = 0.f;
    return z;
}

// ---- MFMA wrapper: tolerate either short8 or bf16x8 builtin signature ----
template <typename A>
__device__ __forceinline__ auto mfma3216_(A a, A b, f32x16 c, int)
    -> decltype(__builtin_amdgcn_mfma_f32_32x32x16_bf16(a, b, c, 0, 0, 0)) {
    return __builtin_amdgcn_mfma_f32_32x32x16_bf16(a, b, c, 0, 0, 0);
}
template <typename A>
__device__ __forceinline__ f32x16 mfma3216_(A a, A b, f32x16 c, long) {
    b16x8 a2 = __builtin_bit_cast(b16x8, a);
    b16x8 b2 = __builtin_bit_cast(b16x8, b);
    return __builtin_amdgcn_mfma_f32_32x32x16_bf16(a2, b2, c, 0, 0, 0);
}
__device__ __forceinline__ f32x16 MFMA(u16x8 a, u16x8 b, f32x16 c) {
    return mfma3216_(__builtin_bit_cast(s16x8, a), __builtin_bit_cast(s16x8, b), c, 0);
}

// ================= P0: per-row stats (fp32, faithful to reference) =================
__global__ void __launch_bounds__(256) prep_rows(const float* __restrict__ Q,
                                                 const float* __restrict__ K,
                                                 const float* __restrict__ cp,
                                                 float* __restrict__ q2g,
                                                 float* __restrict__ k2g,
                                                 float* __restrict__ cfg) {
    const int w = threadIdx.x >> 6, l = threadIdx.x & 63;
    const float c = *cp;
#pragma unroll 1
    for (int p = 0; p < 16; ++p) {
        const int row = blockIdx.x * 64 + p * 4 + w;
        f32x4 qv = *((const f32x4*)(Q + (size_t)row * D_DIM) + l);
        f32x4 kv = *((const f32x4*)(K + (size_t)row * D_DIM) + l);
        float sq = qv[0]*qv[0] + qv[1]*qv[1] + qv[2]*qv[2] + qv[3]*qv[3];
        float sk = kv[0]*kv[0] + kv[1]*kv[1] + kv[2]*kv[2] + kv[3]*kv[3];
#pragma unroll
        for (int m = 1; m < 64; m <<= 1) {
            sq += __shfl_xor(sq, m, 64);
            sk += __shfl_xor(sk, m, 64);
        }
        if (l == 0) {
            q2g[row] = sq;
            k2g[row] = sk;
            float dn = fmaxf((1.f - c * sq) * (1.f - c * sk), 1e-6f);
            cfg[row] = 2.f * c / dn;
        }
    }
}

// ================= P1a: K -> bf16 =================
__global__ void __launch_bounds__(256) cvt_bf16(const float* __restrict__ src,
                                                unsigned short* __restrict__ dst) {
    const size_t i = ((size_t)blockIdx.x * 256 + threadIdx.x) * 8;
    f32x4 a = *(const f32x4*)(src + i);
    f32x4 b = *(const f32x4*)(src + i + 4);
    *(u16x8*)(dst + i) = pack8(a, b);
}

// ================= P1b: V -> bf16, transposed per batch: VT[b][d][j] =================
__global__ void __launch_bounds__(256) transp_v(const float* __restrict__ V,
                                                unsigned short* __restrict__ VT) {
    __shared__ float tile[64][65];
    const int bid = blockIdx.x;
    const int b = bid >> 7, rem = bid & 127, jt = rem >> 2, dt = rem & 3;
    const int j0 = jt * 64, d0 = dt * 64;
    const int t = threadIdx.x;
#pragma unroll
    for (int p = 0; p < 4; ++p) {
        const int jr = p * 16 + (t >> 4);
        f32x4 v = *(const f32x4*)(V + (size_t)(b * S_LEN + j0 + jr) * D_DIM + d0 + (t & 15) * 4);
#pragma unroll
        for (int u = 0; u < 4; ++u) tile[jr][(t & 15) * 4 + u] = v[u];
    }
    __syncthreads();
#pragma unroll
    for (int p = 0; p < 2; ++p) {
        const int dr = p * 32 + (t >> 3), seg = t & 7;
        u16x8 o;
#pragma unroll
        for (int u = 0; u < 8; ++u) o[u] = f2bf(tile[seg * 8 + u][dr]);
        *(u16x8*)(VT + (size_t)(b * D_DIM + d0 + dr) * S_LEN + j0 + seg * 8) = o;
    }
}

// ================= Main fused attention =================
// grid 256, block 256 (4 waves). Block: batch b, 64 q-rows. Wave w: 32 q-rows
// ((w&1) half) x KV-half (w>>1). 32x32x16 bf16 MFMA. No online max needed:
// p = y^(-1/16) in (0,1]. Cross-wave combine (plain sums) via LDS at the end.
template <int PRE>
__global__ void __launch_bounds__(256, 1) hyp_attn(
    const float* __restrict__ Qf, const float* __restrict__ Kf, const float* __restrict__ Vf,
    const unsigned short* __restrict__ Kb, const unsigned short* __restrict__ VTg,
    const float* __restrict__ q2g, const float* __restrict__ k2g, const float* __restrict__ cfg,
    float* __restrict__ out) {
    __shared__ unsigned short Kt[2][64][264];   // 67584 B  (K rows, +8 pad)
    __shared__ unsigned short VTt[2][256][72];  // 73728 B  (V^T rows, +8 pad)
    __shared__ unsigned short Pt[4][32][72];    // 18432 B  (per-wave P transpose)
    __shared__ float lsumBuf[2][32];            // 256 B        => 160000 B total

    const int bid = blockIdx.x;
    const int nb = (bid & 7) * 32 + (bid >> 3);  // XCD-aware swizzle: batch == XCD
    const int b = nb >> 5, rt = nb & 31;
    const int tid = threadIdx.x;
    const int w = tid >> 6, l = tid & 63;
    const int l31 = l & 31, lh = l >> 5;
    const int h = w >> 1;
    const int qr0 = rt * 64 + (w & 1) * 32;
    const int qrow = b * S_LEN + qr0 + l31;

    // ---- Q fragments (A-layout: row=l&31, k=(l>>5)*8+j), fp32->bf16 once ----
    u16x8 qf[16];
    {
        const float* qp = Qf + (size_t)qrow * D_DIM + lh * 8;
#pragma unroll
        for (int ks = 0; ks < 16; ++ks) {
            f32x4 a = *(const f32x4*)(qp + ks * 16);
            f32x4 c4 = *(const f32x4*)(qp + ks * 16 + 4);
            qf[ks] = pack8(a, c4);
        }
    }
    const float q2r = q2g[qrow];
    const float cfr = cfg[qrow];
    float q2v[16], cfv[16];
#pragma unroll
    for (int r = 0; r < 16; ++r) {
        const int rl = (r & 3) + 8 * (r >> 2) + 4 * lh;
        q2v[r] = __shfl(q2r, rl, 32);
        cfv[r] = __shfl(cfr, rl, 32);
    }

    f32x16 oacc[8];
#pragma unroll
    for (int i = 0; i < 8; ++i) oacc[i] = zero16();
    float lsum[16];
#pragma unroll
    for (int r = 0; r < 16; ++r) lsum[r] = 0.f;

    const size_t kbBase = (size_t)b * S_LEN * D_DIM;

    for (int it = 0; it < 16; ++it) {
        __syncthreads();
        const int jb0 = it * 64;  // within each 1024-wide half
        if (PRE) {
#pragma unroll
            for (int p = 0; p < 16; ++p) {  // K tiles, both halves
                const int cc = p * 256 + tid;
                const int hh = cc >> 11, rr = (cc >> 5) & 63, seg = cc & 31;
                u16x8 v = *(const u16x8*)(Kb + kbBase + (size_t)(hh * 1024 + jb0 + rr) * D_DIM + seg * 8);
                *(u16x8*)&Kt[hh][rr][seg * 8] = v;
            }
#pragma unroll
            for (int p = 0; p < 16; ++p) {  // V^T tiles, both halves
                const int cc = p * 256 + tid;
                const int hh = cc >> 11, dr = (cc >> 3) & 255, seg = cc & 7;
                u16x8 v = *(const u16x8*)(VTg + ((size_t)b * D_DIM + dr) * S_LEN + hh * 1024 + jb0 + seg * 8);
                *(u16x8*)&VTt[hh][dr][seg * 8] = v;
            }
        } else {
#pragma unroll
            for (int p = 0; p < 16; ++p) {
                const int cc = p * 256 + tid;
                const int hh = cc >> 11, rr = (cc >> 5) & 63, seg = cc & 31;
                const float* sp = Kf + kbBase + (size_t)(hh * 1024 + jb0 + rr) * D_DIM + seg * 8;
                f32x4 a = *(const f32x4*)sp;
                f32x4 c4 = *(const f32x4*)(sp + 4);
                *(u16x8*)&Kt[hh][rr][seg * 8] = pack8(a, c4);
            }
#pragma unroll
            for (int p = 0; p < 32; ++p) {
                const int cc = p * 256 + tid;
                const int j = cc & 63, d4 = (cc >> 6) & 63, hh = cc >> 12;
                f32x4 v = *(const f32x4*)(Vf + kbBase + (size_t)(hh * 1024 + jb0 + j) * D_DIM + d4 * 4);
#pragma unroll
                for (int u = 0; u < 4; ++u) VTt[hh][d4 * 4 + u][j] = f2bf(v[u]);
            }
        }
        __syncthreads();

        // ---- QK^T + hyperbolic logits + p, per 32-wide j-block ----
#pragma unroll
        for (int jblk = 0; jblk < 2; ++jblk) {
            const float k2c = k2g[b * S_LEN + h * 1024 + jb0 + jblk * 32 + l31];
            f32x16 sacc = zero16();
#pragma unroll
            for (int ks = 0; ks < 16; ++ks) {
                u16x8 kf = *(const u16x8*)&Kt[h][jblk * 32 + l31][ks * 16 + lh * 8];
                sacc = MFMA(qf[ks], kf, sacc);
            }
#pragma unroll
            for (int r = 0; r < 16; ++r) {
                const int rl = (r & 3) + 8 * (r >> 2) + 4 * lh;
                const float t = fmaf(-2.f, sacc[r], q2v[r] + k2c);   // q2+k2-2qk (nd2, pre-clamp)
                const float arg = fmaxf(fmaf(cfv[r], t, 1.f), 1.f + 1e-6f);
                const float y = arg + sqrtf(fmaf(arg, arg, -1.f));   // arccosh arg -> y
                // p = y^(-1/16) = sqrt(sqrt(sqrt(rsqrt(y)))) — no exp/log needed
                const float p = sqrtf(sqrtf(sqrtf(rsqrtf(y))));
                lsum[r] += p;
                Pt[w][rl][jblk * 32 + l31] = f2bf(p);
            }
        }
        // ---- PV: O += P * V ----
#pragma unroll
        for (int ks2 = 0; ks2 < 4; ++ks2) {
            u16x8 pf = *(const u16x8*)&Pt[w][l31][ks2 * 16 + lh * 8];
#pragma unroll
            for (int db = 0; db < 8; ++db) {
                u16x8 vf = *(const u16x8*)&VTt[h][db * 32 + l31][ks2 * 16 + lh * 8];
                oacc[db] = MFMA(pf, vf, oacc[db]);
            }
        }
    }

    // ---- row-sum of lsum over the 32 columns ----
#pragma unroll
    for (int r = 0; r < 16; ++r) {
#pragma unroll
        for (int m = 1; m < 32; m <<= 1) lsum[r] += __shfl_xor(lsum[r], m, 32);
    }

    __syncthreads();
    float* cbuf = (float*)&Kt[0][0][0];  // 64 KB scratch, safe after final barrier
    if (w >= 2) {
        const int ro = (w & 1) * 8192;
#pragma unroll
        for (int db = 0; db < 8; ++db) {
#pragma unroll
            for (int r = 0; r < 16; ++r) {
                const int rl = (r & 3) + 8 * (r >> 2) + 4 * lh;
                cbuf[ro + rl * 256 + db * 32 + l31] = oacc[db][r];
            }
        }
        if (l31 == 0) {
#pragma unroll
            for (int r = 0; r < 16; ++r) {
                const int rl = (r & 3) + 8 * (r >> 2) + 4 * lh;
                lsumBuf[w & 1][rl] = lsum[r];
            }
        }
    }
    __syncthreads();
    if (w < 2) {
        float rdn[16];
#pragma unroll
        for (int r = 0; r < 16; ++r) {
            const int rl = (r & 3) + 8 * (r >> 2) + 4 * lh;
            rdn[r] = 1.0f / (lsum[r] + lsumBuf[w][rl]);
        }
#pragma unroll
        for (int db = 0; db < 8; ++db) {
#pragma unroll
            for (int r = 0; r < 16; ++r) {
                const int rl = (r & 3) + 8 * (r >> 2) + 4 * lh;
                const float o = oacc[db][r] + cbuf[w * 8192 + rl * 256 + db * 32 + l31];
                out[(size_t)(b * S_LEN + qr0 + rl) * D_DIM + db * 32 + l31] = o * rdn[r];
            }
        }
    }
}

// ================= launcher =================
extern "C" void kernel_launch(void* const* d_in, const int* in_sizes, int n_in,
                              void* d_out, int out_size, void* d_ws, size_t ws_size,
                              hipStream_t stream) {
    const float* Q = (const float*)d_in[0];
    const float* K = (const float*)d_in[1];
    const float* V = (const float*)d_in[2];
    const float* cp = (const float*)d_in[3];
    float* out = (float*)d_out;
    (void)in_sizes; (void)n_in; (void)out_size;

    const size_t BS = (size_t)B_N * S_LEN;
    float* q2g = (float*)d_ws;
    float* k2g = q2g + BS;
    float* cfg = k2g + BS;
    unsigned short* Kb = (unsigned short*)(cfg + BS);
    unsigned short* VTg = Kb + BS * D_DIM;
    const size_t need_full = 3 * BS * 4 + 2 * BS * D_DIM * 2;  // ~17 MB

    prep_rows<<<(B_N * S_LEN) / 64, 256, 0, stream>>>(Q, K, cp, q2g, k2g, cfg);

    if (ws_size >= need_full) {
        cvt_bf16<<<(int)((BS * D_DIM / 8) / 256), 256, 0, stream>>>(K, Kb);
        transp_v<<<B_N * (S_LEN / 64) * (D_DIM / 64), 256, 0, stream>>>(V, VTg);
        hyp_attn<1><<<256, 256, 0, stream>>>(Q, K, V, Kb, VTg, q2g, k2g, cfg, out);
    } else {
        hyp_attn<0><<<256, 256, 0, stream>>>(Q, K, V, Kb, VTg, q2g, k2g, cfg, out);
    }
}

// Round 3
// 188.411 us; speedup vs baseline: 1.2634x; 1.2634x over previous
//
#include <hip/hip_runtime.h>

#define B_N   8
#define S_LEN 2048
#define D_DIM 256
#define Q4    512   // KV quarter length
#define JT    32    // j-tile per iteration
#define NIT   16    // Q4/JT

typedef __attribute__((ext_vector_type(4)))  float          f32x4;
typedef __attribute__((ext_vector_type(16))) float          f32x16;
typedef __attribute__((ext_vector_type(8)))  short          s16x8;
typedef __attribute__((ext_vector_type(8)))  __bf16         b16x8;
typedef __attribute__((ext_vector_type(8)))  unsigned short u16x8;
typedef __attribute__((ext_vector_type(4)))  unsigned int   u32x4;

// ---- bf16 helpers (RNE) ----
__device__ __forceinline__ unsigned short f2bf(float f) {
    unsigned u = __builtin_bit_cast(unsigned, f);
    u += 0x7FFFu + ((u >> 16) & 1u);
    return (unsigned short)(u >> 16);
}
__device__ __forceinline__ u16x8 pack8(f32x4 a, f32x4 b) {
    u16x8 o;
#pragma unroll
    for (int u = 0; u < 4; ++u) { o[u] = f2bf(a[u]); o[u + 4] = f2bf(b[u]); }
    return o;
}
__device__ __forceinline__ f32x16 zero16() {
    f32x16 z;
#pragma unroll
    for (int i = 0; i < 16; ++i) z[i] = 0.f;
    return z;
}
// packed f32->bf16 pair (HW RNE), no builtin on gfx950 -> asm
__device__ __forceinline__ unsigned cvtpk(float lo, float hi) {
    unsigned r;
    asm("v_cvt_pk_bf16_f32 %0, %1, %2" : "=v"(r) : "v"(lo), "v"(hi));
    return r;
}
// exchange (lane l: y) <-> (lane l+32: x)
__device__ __forceinline__ void xswap(unsigned& x, unsigned& y, int lh) {
    unsigned vs = lh ? x : y;
    unsigned vr = (unsigned)__shfl_xor((int)vs, 32, 64);
    x = lh ? vr : x;
    y = lh ? y : vr;
}

// ---- MFMA wrapper: tolerate either short8 or bf16x8 builtin signature ----
template <typename A>
__device__ __forceinline__ auto mfma3216_(A a, A b, f32x16 c, int)
    -> decltype(__builtin_amdgcn_mfma_f32_32x32x16_bf16(a, b, c, 0, 0, 0)) {
    return __builtin_amdgcn_mfma_f32_32x32x16_bf16(a, b, c, 0, 0, 0);
}
template <typename A>
__device__ __forceinline__ f32x16 mfma3216_(A a, A b, f32x16 c, long) {
    b16x8 a2 = __builtin_bit_cast(b16x8, a);
    b16x8 b2 = __builtin_bit_cast(b16x8, b);
    return __builtin_amdgcn_mfma_f32_32x32x16_bf16(a2, b2, c, 0, 0, 0);
}
__device__ __forceinline__ f32x16 MFMA(u16x8 a, u16x8 b, f32x16 c) {
    return mfma3216_(__builtin_bit_cast(s16x8, a), __builtin_bit_cast(s16x8, b), c, 0);
}

// ================= P0: per-row stats (fp32, faithful to reference) =================
__global__ void __launch_bounds__(256) prep_rows(const float* __restrict__ Q,
                                                 const float* __restrict__ K,
                                                 const float* __restrict__ cp,
                                                 float* __restrict__ q2g,
                                                 float* __restrict__ k2g,
                                                 float* __restrict__ cfg) {
    const int w = threadIdx.x >> 6, l = threadIdx.x & 63;
    const float c = *cp;
#pragma unroll 1
    for (int p = 0; p < 16; ++p) {
        const int row = blockIdx.x * 64 + p * 4 + w;
        f32x4 qv = *((const f32x4*)(Q + (size_t)row * D_DIM) + l);
        f32x4 kv = *((const f32x4*)(K + (size_t)row * D_DIM) + l);
        float sq = qv[0]*qv[0] + qv[1]*qv[1] + qv[2]*qv[2] + qv[3]*qv[3];
        float sk = kv[0]*kv[0] + kv[1]*kv[1] + kv[2]*kv[2] + kv[3]*kv[3];
#pragma unroll
        for (int m = 1; m < 64; m <<= 1) {
            sq += __shfl_xor(sq, m, 64);
            sk += __shfl_xor(sk, m, 64);
        }
        if (l == 0) {
            q2g[row] = sq;
            k2g[row] = sk;
            float dn = fmaxf((1.f - c * sq) * (1.f - c * sk), 1e-6f);
            cfg[row] = 2.f * c / dn;
        }
    }
}

// ================= P1a: K -> bf16 =================
__global__ void __launch_bounds__(256) cvt_bf16(const float* __restrict__ src,
                                                unsigned short* __restrict__ dst) {
    const size_t i = ((size_t)blockIdx.x * 256 + threadIdx.x) * 8;
    f32x4 a = *(const f32x4*)(src + i);
    f32x4 b = *(const f32x4*)(src + i + 4);
    *(u16x8*)(dst + i) = pack8(a, b);
}

// ================= P1b: V -> bf16, transposed per batch: VT[b][d][j] =================
__global__ void __launch_bounds__(256) transp_v(const float* __restrict__ V,
                                                unsigned short* __restrict__ VT) {
    __shared__ float tile[64][65];
    const int bid = blockIdx.x;
    const int b = bid >> 7, rem = bid & 127, jt = rem >> 2, dt = rem & 3;
    const int j0 = jt * 64, d0 = dt * 64;
    const int t = threadIdx.x;
#pragma unroll
    for (int p = 0; p < 4; ++p) {
        const int jr = p * 16 + (t >> 4);
        f32x4 v = *(const f32x4*)(V + (size_t)(b * S_LEN + j0 + jr) * D_DIM + d0 + (t & 15) * 4);
#pragma unroll
        for (int u = 0; u < 4; ++u) tile[jr][(t & 15) * 4 + u] = v[u];
    }
    __syncthreads();
#pragma unroll
    for (int p = 0; p < 2; ++p) {
        const int dr = p * 32 + (t >> 3), seg = t & 7;
        u16x8 o;
#pragma unroll
        for (int u = 0; u < 8; ++u) o[u] = f2bf(tile[seg * 8 + u][dr]);
        *(u16x8*)(VT + (size_t)(b * D_DIM + d0 + dr) * S_LEN + j0 + seg * 8) = o;
    }
}

// ================= Main fused attention =================
// grid 256 (XCD-swizzled, batch==XCD), block 512 (8 waves). Wave w: q-group
// qg=w&1 (32 rows), KV-quarter qt=w>>1. Swapped QK^T: sacc[r]=S[j=crow][q=l31]
// -> q2/cf per-lane scalars, scalar lsum, in-register P transpose via
// cvt_pk_bf16 + shfl_xor(32). p = y^(-1/16) in (0,1]: no online max needed.
template <int PRE>
__global__ void __launch_bounds__(512, 2) hyp_attn(
    const float* __restrict__ Qf, const float* __restrict__ Kf, const float* __restrict__ Vf,
    const unsigned short* __restrict__ Kb, const unsigned short* __restrict__ VTg,
    const float* __restrict__ q2g, const float* __restrict__ k2g, const float* __restrict__ cfg,
    float* __restrict__ out) {
    // carved LDS: Kt[4][32][264] (67584B) + VTt[4][256][40] (81920B) = 149504B
    __shared__ __align__(16) unsigned short smem[74752];
    __shared__ float k2sh[S_LEN];        // 8192 B
    __shared__ float lsumBuf[4][2][32];  // 1024 B   => 158720 B total
    auto Kt  = (unsigned short(*)[32][264])smem;
    auto VTt = (unsigned short(*)[256][40])(smem + 33792);

    const int bid = blockIdx.x;
    const int nb = (bid & 7) * 32 + (bid >> 3);  // batch == XCD
    const int b = nb >> 5, rt = nb & 31;
    const int tid = threadIdx.x;
    const int w = tid >> 6, l = tid & 63;
    const int l31 = l & 31, lh = l >> 5;
    const int qg = w & 1, qt = w >> 1;
    const int qr0 = rt * 64 + qg * 32;
    const int qrow = b * S_LEN + qr0 + l31;

    // stage batch k2 once (visibility via first loop barrier)
    *(f32x4*)&k2sh[tid * 4] = *(const f32x4*)(k2g + b * S_LEN + tid * 4);

    // ---- Q fragments (row=l31, k=lh*8+j), fp32->bf16 once ----
    u16x8 qf[16];
    {
        const float* qp = Qf + (size_t)qrow * D_DIM + lh * 8;
#pragma unroll
        for (int ks = 0; ks < 16; ++ks) {
            f32x4 a = *(const f32x4*)(qp + ks * 16);
            f32x4 c4 = *(const f32x4*)(qp + ks * 16 + 4);
            qf[ks] = pack8(a, c4);
        }
    }
    const float q2r = q2g[qrow];
    const float cfr = cfg[qrow];
    const float base1 = fmaf(cfr, q2r, 1.0f);  // 1 + cf*q2

    f32x16 oacc[8];
#pragma unroll
    for (int i = 0; i < 8; ++i) oacc[i] = zero16();
    float lsum = 0.f;

    const size_t kbBase = (size_t)b * S_LEN * D_DIM;

    for (int it = 0; it < NIT; ++it) {
        __syncthreads();
        const int jb0 = it * JT;
        if (PRE) {
#pragma unroll
            for (int p = 0; p < 8; ++p) {  // K: 4q x 32r x 32seg
                const int cc = p * 512 + tid;
                const int qc = cc >> 10, rr = (cc >> 5) & 31, seg = cc & 31;
                *(u16x8*)&Kt[qc][rr][seg * 8] =
                    *(const u16x8*)(Kb + kbBase + (size_t)(qc * Q4 + jb0 + rr) * D_DIM + seg * 8);
            }
#pragma unroll
            for (int p = 0; p < 8; ++p) {  // VT: 4q x 256d x 4seg
                const int cc = p * 512 + tid;
                const int qc = cc >> 10, dr = (cc >> 2) & 255, seg = cc & 3;
                *(u16x8*)&VTt[qc][dr][seg * 8] =
                    *(const u16x8*)(VTg + ((size_t)b * D_DIM + dr) * S_LEN + qc * Q4 + jb0 + seg * 8);
            }
        } else {
#pragma unroll
            for (int p = 0; p < 8; ++p) {  // K from fp32
                const int cc = p * 512 + tid;
                const int qc = cc >> 10, rr = (cc >> 5) & 31, seg = cc & 31;
                const float* sp = Kf + kbBase + (size_t)(qc * Q4 + jb0 + rr) * D_DIM + seg * 8;
                *(u16x8*)&Kt[qc][rr][seg * 8] = pack8(*(const f32x4*)sp, *(const f32x4*)(sp + 4));
            }
#pragma unroll
            for (int p = 0; p < 8; ++p) {  // V transpose: 4q x 32j x 32dgrp
                const int cc = p * 512 + tid;
                const int qc = cc >> 10, jj = (cc >> 5) & 31, dg = cc & 31;
                const float* sp = Vf + kbBase + (size_t)(qc * Q4 + jb0 + jj) * D_DIM + dg * 8;
                f32x4 a = *(const f32x4*)sp, c4 = *(const f32x4*)(sp + 4);
#pragma unroll
                for (int u = 0; u < 4; ++u) {
                    VTt[qc][dg * 8 + u][jj] = f2bf(a[u]);
                    VTt[qc][dg * 8 + 4 + u][jj] = f2bf(c4[u]);
                }
            }
        }
        __syncthreads();

        // ---- swapped QK^T: sacc[r] = S[j=crow(r,lh)][q=l31] ----
        f32x16 sacc = zero16();
#pragma unroll
        for (int ks = 0; ks < 16; ++ks) {
            u16x8 kf = *(const u16x8*)&Kt[qt][l31][ks * 16 + lh * 8];
            sacc = MFMA(kf, qf[ks], sacc);
        }

        // ---- hyperbolic logits -> p (per-lane: one q-row) ----
        float pv[16];
#pragma unroll
        for (int r = 0; r < 16; ++r) {
            const int crow = (r & 3) + 8 * (r >> 2) + 4 * lh;
            const float k2j = k2sh[qt * Q4 + jb0 + crow];
            const float t = fmaf(-2.f, sacc[r], k2j);                 // k2 - 2S
            const float arg = fmaxf(fmaf(cfr, t, base1), 1.f + 1e-6f);
            const float y = arg + sqrtf(fmaf(arg, arg, -1.f));        // e^{arccosh}
            const float p = sqrtf(sqrtf(sqrtf(rsqrtf(y))));           // y^(-1/16)
            lsum += p;
            pv[r] = p;
        }

        // ---- in-register P transpose: lane gets A-frag rows (q=l31) ----
        unsigned A_ = cvtpk(pv[0], pv[1]),   C_ = cvtpk(pv[2], pv[3]);
        unsigned Bv = cvtpk(pv[4], pv[5]),   D_ = cvtpk(pv[6], pv[7]);
        unsigned E_ = cvtpk(pv[8], pv[9]),   G_ = cvtpk(pv[10], pv[11]);
        unsigned F_ = cvtpk(pv[12], pv[13]), H_ = cvtpk(pv[14], pv[15]);
        xswap(A_, Bv, lh); xswap(C_, D_, lh);
        xswap(E_, F_, lh); xswap(G_, H_, lh);
        const u16x8 pa0 = __builtin_bit_cast(u16x8, (u32x4){A_, C_, Bv, D_});
        const u16x8 pa1 = __builtin_bit_cast(u16x8, (u32x4){E_, G_, F_, H_});

        // ---- PV: O += P * V ----
#pragma unroll
        for (int db = 0; db < 8; ++db) {
            u16x8 vf0 = *(const u16x8*)&VTt[qt][db * 32 + l31][lh * 8];
            oacc[db] = MFMA(pa0, vf0, oacc[db]);
            u16x8 vf1 = *(const u16x8*)&VTt[qt][db * 32 + l31][16 + lh * 8];
            oacc[db] = MFMA(pa1, vf1, oacc[db]);
        }
    }

    // ---- epilogue: combine 4 KV-quarter partials ----
    lsum += __shfl_xor(lsum, 32, 64);  // join lh halves: total per q=l31 (this qt)
    __syncthreads();                    // all LDS tile reads done
    if (lh == 0) lsumBuf[qt][qg][l31] = lsum;
    float* sf = (float*)smem;  // 4 slots x 32q x 256d fp32 = 128KB <= 149.5KB
    if (qt >= 2) {
        const int slot = (qt - 2) * 2 + qg;
#pragma unroll
        for (int db = 0; db < 8; ++db)
#pragma unroll
            for (int r = 0; r < 16; ++r) {
                const int crow = (r & 3) + 8 * (r >> 2) + 4 * lh;
                sf[slot * 8192 + crow * 256 + db * 32 + l31] = oacc[db][r];
            }
    }
    __syncthreads();
    if (qt <= 1) {
        const int slot = qt * 2 + qg;
#pragma unroll
        for (int db = 0; db < 8; ++db)
#pragma unroll
            for (int r = 0; r < 16; ++r) {
                const int crow = (r & 3) + 8 * (r >> 2) + 4 * lh;
                oacc[db][r] += sf[slot * 8192 + crow * 256 + db * 32 + l31];
            }
    }
    __syncthreads();
    if (qt == 1) {
#pragma unroll
        for (int db = 0; db < 8; ++db)
#pragma unroll
            for (int r = 0; r < 16; ++r) {
                const int crow = (r & 3) + 8 * (r >> 2) + 4 * lh;
                sf[qg * 8192 + crow * 256 + db * 32 + l31] = oacc[db][r];
            }
    }
    __syncthreads();
    if (qt == 0) {
        float rdn[16];
#pragma unroll
        for (int r = 0; r < 16; ++r) {
            const int crow = (r & 3) + 8 * (r >> 2) + 4 * lh;
            rdn[r] = 1.0f / (lsumBuf[0][qg][crow] + lsumBuf[1][qg][crow] +
                             lsumBuf[2][qg][crow] + lsumBuf[3][qg][crow]);
        }
#pragma unroll
        for (int db = 0; db < 8; ++db)
#pragma unroll
            for (int r = 0; r < 16; ++r) {
                const int crow = (r & 3) + 8 * (r >> 2) + 4 * lh;
                const float o = oacc[db][r] + sf[qg * 8192 + crow * 256 + db * 32 + l31];
                out[(size_t)(b * S_LEN + qr0 + crow) * D_DIM + db * 32 + l31] = o * rdn[r];
            }
    }
}

// ================= launcher =================
extern "C" void kernel_launch(void* const* d_in, const int* in_sizes, int n_in,
                              void* d_out, int out_size, void* d_ws, size_t ws_size,
                              hipStream_t stream) {
    const float* Q = (const float*)d_in[0];
    const float* K = (const float*)d_in[1];
    const float* V = (const float*)d_in[2];
    const float* cp = (const float*)d_in[3];
    float* out = (float*)d_out;
    (void)in_sizes; (void)n_in; (void)out_size;

    const size_t BS = (size_t)B_N * S_LEN;
    float* q2g = (float*)d_ws;
    float* k2g = q2g + BS;
    float* cfg = k2g + BS;
    unsigned short* Kb = (unsigned short*)(cfg + BS);
    unsigned short* VTg = Kb + BS * D_DIM;
    const size_t need_full = 3 * BS * 4 + 2 * BS * D_DIM * 2;  // ~17 MB

    prep_rows<<<(B_N * S_LEN) / 64, 256, 0, stream>>>(Q, K, cp, q2g, k2g, cfg);

    if (ws_size >= need_full) {
        cvt_bf16<<<(int)((BS * D_DIM / 8) / 256), 256, 0, stream>>>(K, Kb);
        transp_v<<<B_N * (S_LEN / 64) * (D_DIM / 64), 256, 0, stream>>>(V, VTg);
        hyp_attn<1><<<256, 512, 0, stream>>>(Q, K, V, Kb, VTg, q2g, k2g, cfg, out);
    } else {
        hyp_attn<0><<<256, 512, 0, stream>>>(Q, K, V, Kb, VTg, q2g, k2g, cfg, out);
    }
}

// Round 4
// 129.467 us; speedup vs baseline: 1.8386x; 1.4553x over previous
//
#include <hip/hip_runtime.h>

#define B_N   8
#define S_LEN 2048
#define D_DIM 256
#define Q4    512   // KV quarter length
#define JT    32    // j-tile per iteration
#define NIT   16    // Q4/JT

typedef __attribute__((ext_vector_type(4)))  float          f32x4;
typedef __attribute__((ext_vector_type(16))) float          f32x16;
typedef __attribute__((ext_vector_type(8)))  short          s16x8;
typedef __attribute__((ext_vector_type(8)))  __bf16         b16x8;
typedef __attribute__((ext_vector_type(8)))  unsigned short u16x8;
typedef __attribute__((ext_vector_type(4)))  unsigned int   u32x4;

// ---- bf16 helpers (RNE) ----
__device__ __forceinline__ unsigned short f2bf(float f) {
    unsigned u = __builtin_bit_cast(unsigned, f);
    u += 0x7FFFu + ((u >> 16) & 1u);
    return (unsigned short)(u >> 16);
}
__device__ __forceinline__ u16x8 pack8(f32x4 a, f32x4 b) {
    u16x8 o;
#pragma unroll
    for (int u = 0; u < 4; ++u) { o[u] = f2bf(a[u]); o[u + 4] = f2bf(b[u]); }
    return o;
}
__device__ __forceinline__ f32x16 zero16() {
    f32x16 z;
#pragma unroll
    for (int i = 0; i < 16; ++i) z[i] = 0.f;
    return z;
}
// packed f32->bf16 pair (HW RNE), no builtin on gfx950 -> asm
__device__ __forceinline__ unsigned cvtpk(float lo, float hi) {
    unsigned r;
    asm("v_cvt_pk_bf16_f32 %0, %1, %2" : "=v"(r) : "v"(lo), "v"(hi));
    return r;
}
// exchange (lane l: y) <-> (lane l+32: x)
__device__ __forceinline__ void xswap(unsigned& x, unsigned& y, int lh) {
    unsigned vs = lh ? x : y;
    unsigned vr = (unsigned)__shfl_xor((int)vs, 32, 64);
    x = lh ? vr : x;
    y = lh ? y : vr;
}
// raw HW transcendentals (VOP1): ~1 ulp, no IEEE fixup sequences
__device__ __forceinline__ float hw_sqrt(float x) {
    float r; asm("v_sqrt_f32 %0, %1" : "=v"(r) : "v"(x)); return r;
}
__device__ __forceinline__ float hw_log2(float x) {
    float r; asm("v_log_f32 %0, %1" : "=v"(r) : "v"(x)); return r;
}
__device__ __forceinline__ float hw_exp2(float x) {
    float r; asm("v_exp_f32 %0, %1" : "=v"(r) : "v"(x)); return r;
}
// async global->LDS, 16B per lane, dest = wave-uniform base + lane*16 (linear)
__device__ __forceinline__ void gload16(const void* g, void* l) {
    __builtin_amdgcn_global_load_lds((const __attribute__((address_space(1))) void*)g,
                                     (__attribute__((address_space(3))) void*)l, 16, 0, 0);
}

// ---- MFMA wrapper: tolerate either short8 or bf16x8 builtin signature ----
template <typename A>
__device__ __forceinline__ auto mfma3216_(A a, A b, f32x16 c, int)
    -> decltype(__builtin_amdgcn_mfma_f32_32x32x16_bf16(a, b, c, 0, 0, 0)) {
    return __builtin_amdgcn_mfma_f32_32x32x16_bf16(a, b, c, 0, 0, 0);
}
template <typename A>
__device__ __forceinline__ f32x16 mfma3216_(A a, A b, f32x16 c, long) {
    b16x8 a2 = __builtin_bit_cast(b16x8, a);
    b16x8 b2 = __builtin_bit_cast(b16x8, b);
    return __builtin_amdgcn_mfma_f32_32x32x16_bf16(a2, b2, c, 0, 0, 0);
}
__device__ __forceinline__ f32x16 MFMA(u16x8 a, u16x8 b, f32x16 c) {
    return mfma3216_(__builtin_bit_cast(s16x8, a), __builtin_bit_cast(s16x8, b), c, 0);
}

// ================= P0: per-row stats (fp32, faithful to reference) =================
__global__ void __launch_bounds__(256) prep_rows(const float* __restrict__ Q,
                                                 const float* __restrict__ K,
                                                 const float* __restrict__ cp,
                                                 float* __restrict__ q2g,
                                                 float* __restrict__ k2g,
                                                 float* __restrict__ cfg) {
    const int w = threadIdx.x >> 6, l = threadIdx.x & 63;
    const float c = *cp;
#pragma unroll 1
    for (int p = 0; p < 16; ++p) {
        const int row = blockIdx.x * 64 + p * 4 + w;
        f32x4 qv = *((const f32x4*)(Q + (size_t)row * D_DIM) + l);
        f32x4 kv = *((const f32x4*)(K + (size_t)row * D_DIM) + l);
        float sq = qv[0]*qv[0] + qv[1]*qv[1] + qv[2]*qv[2] + qv[3]*qv[3];
        float sk = kv[0]*kv[0] + kv[1]*kv[1] + kv[2]*kv[2] + kv[3]*kv[3];
#pragma unroll
        for (int m = 1; m < 64; m <<= 1) {
            sq += __shfl_xor(sq, m, 64);
            sk += __shfl_xor(sk, m, 64);
        }
        if (l == 0) {
            q2g[row] = sq;
            k2g[row] = sk;
            float dn = fmaxf((1.f - c * sq) * (1.f - c * sk), 1e-6f);
            cfg[row] = 2.f * c / dn;
        }
    }
}

// ================= P1a: K -> bf16 =================
__global__ void __launch_bounds__(256) cvt_bf16(const float* __restrict__ src,
                                                unsigned short* __restrict__ dst) {
    const size_t i = ((size_t)blockIdx.x * 256 + threadIdx.x) * 8;
    f32x4 a = *(const f32x4*)(src + i);
    f32x4 b = *(const f32x4*)(src + i + 4);
    *(u16x8*)(dst + i) = pack8(a, b);
}

// ================= P1b: V -> bf16, transposed per batch: VT[b][d][j] =================
__global__ void __launch_bounds__(256) transp_v(const float* __restrict__ V,
                                                unsigned short* __restrict__ VT) {
    __shared__ float tile[64][65];
    const int bid = blockIdx.x;
    const int b = bid >> 7, rem = bid & 127, jt = rem >> 2, dt = rem & 3;
    const int j0 = jt * 64, d0 = dt * 64;
    const int t = threadIdx.x;
#pragma unroll
    for (int p = 0; p < 4; ++p) {
        const int jr = p * 16 + (t >> 4);
        f32x4 v = *(const f32x4*)(V + (size_t)(b * S_LEN + j0 + jr) * D_DIM + d0 + (t & 15) * 4);
#pragma unroll
        for (int u = 0; u < 4; ++u) tile[jr][(t & 15) * 4 + u] = v[u];
    }
    __syncthreads();
#pragma unroll
    for (int p = 0; p < 2; ++p) {
        const int dr = p * 32 + (t >> 3), seg = t & 7;
        u16x8 o;
#pragma unroll
        for (int u = 0; u < 8; ++u) o[u] = f2bf(tile[seg * 8 + u][dr]);
        *(u16x8*)(VT + (size_t)(b * D_DIM + d0 + dr) * S_LEN + j0 + seg * 8) = o;
    }
}

// ================= Main fused attention =================
// grid 256 (XCD-swizzled, batch==XCD), block 512 (8 waves). Wave w: q-group
// qg=w&1 (32 rows), KV-quarter qt=w>>1. Swapped QK^T (verified r3). Tiles are
// UNPADDED + XOR-swizzled (Kt: byte^=(row&7)<<4, VT: byte^=(row&3)<<4), staged
// via global_load_lds from pre-swizzled global addresses (rule #21).
// Kt[4][32][256] @0 (64K) | VTt[4][256][32] @64K (64K) | k2sh 8K | lsumBuf 1K.
template <int PRE>
__global__ void __launch_bounds__(512, 2) hyp_attn(
    const float* __restrict__ Qf, const float* __restrict__ Kf, const float* __restrict__ Vf,
    const unsigned short* __restrict__ Kb, const unsigned short* __restrict__ VTg,
    const float* __restrict__ q2g, const float* __restrict__ k2g, const float* __restrict__ cfg,
    float* __restrict__ out) {
    __shared__ __align__(1024) unsigned char tiles[131072];
    __shared__ float k2sh[S_LEN];        // 8192 B
    __shared__ float lsumBuf[4][2][32];  // 1024 B   => 140288 B total

    const int bid = blockIdx.x;
    const int nb = (bid & 7) * 32 + (bid >> 3);  // batch == XCD
    const int b = nb >> 5, rt = nb & 31;
    const int tid = threadIdx.x;
    const int w = tid >> 6, l = tid & 63;
    const int l31 = l & 31, lh = l >> 5;
    const int qg = w & 1, qt = w >> 1;
    const int qr0 = rt * 64 + qg * 32;
    const int qrow = b * S_LEN + qr0 + l31;

    // stage batch k2 once (visibility via first loop barrier)
    *(f32x4*)&k2sh[tid * 4] = *(const f32x4*)(k2g + b * S_LEN + tid * 4);

    // ---- Q fragments (B-operand: col=l31, k=lh*8+j), fp32->bf16 once ----
    u16x8 qf[16];
    {
        const float* qp = Qf + (size_t)qrow * D_DIM + lh * 8;
#pragma unroll
        for (int ks = 0; ks < 16; ++ks) {
            f32x4 a = *(const f32x4*)(qp + ks * 16);
            f32x4 c4 = *(const f32x4*)(qp + ks * 16 + 4);
            qf[ks] = pack8(a, c4);
        }
    }
    const float q2r = q2g[qrow];
    const float cfr = cfg[qrow];
    const float base1 = fmaf(cfr, q2r, 1.0f);  // 1 + cf*q2

    f32x16 oacc[8];
#pragma unroll
    for (int i = 0; i < 8; ++i) oacc[i] = zero16();
    float lsum = 0.f;

    const size_t kbBase = (size_t)b * S_LEN * D_DIM;
    const int xk = (l31 & 7) << 4;  // Kt read swizzle
    const int xv = (l31 & 3) << 4;  // VTt read swizzle
    const char* kq = (const char*)tiles + qt * 16384 + l31 * 512;
    const char* vq = (const char*)tiles + 65536 + qt * 16384 + l31 * 64;

#pragma unroll 1
    for (int it = 0; it < NIT; ++it) {
        __syncthreads();
        const int jb0 = it * JT;
        if (PRE) {
#pragma unroll
            for (int p = 0; p < 8; ++p) {  // K: 4q x 32r x 32 slots(16B)
                const int cc = p * 512 + tid;
                const int qc = cc >> 10, rr = (cc >> 5) & 31, seg = cc & 31;
                const unsigned short* gp = Kb + kbBase + (size_t)(qc * Q4 + jb0 + rr) * D_DIM
                                         + ((seg ^ (rr & 7)) << 3);
                gload16(gp, (char*)tiles + cc * 16);
            }
#pragma unroll
            for (int p = 0; p < 8; ++p) {  // VT: 4q x 256d x 4 slots(16B)
                const int cc = p * 512 + tid;
                const int qc = cc >> 10, dr = (cc >> 2) & 255, sl = cc & 3;
                const unsigned short* gp = VTg + ((size_t)b * D_DIM + dr) * S_LEN
                                         + qc * Q4 + jb0 + ((sl ^ (dr & 3)) << 3);
                gload16(gp, (char*)tiles + 65536 + cc * 16);
            }
        } else {
#pragma unroll
            for (int p = 0; p < 8; ++p) {  // K from fp32, swizzled source col
                const int cc = p * 512 + tid;
                const int qc = cc >> 10, rr = (cc >> 5) & 31, seg = cc & 31;
                const float* sp = Kf + kbBase + (size_t)(qc * Q4 + jb0 + rr) * D_DIM
                                + ((seg ^ (rr & 7)) << 3);
                *(u16x8*)((char*)tiles + cc * 16) = pack8(*(const f32x4*)sp, *(const f32x4*)(sp + 4));
            }
#pragma unroll
            for (int p = 0; p < 8; ++p) {  // V transpose, per-element swizzled writes
                const int cc = p * 512 + tid;
                const int qc = cc >> 10, jj = (cc >> 5) & 31, dg = cc & 31;
                const float* sp = Vf + kbBase + (size_t)(qc * Q4 + jb0 + jj) * D_DIM + dg * 8;
                f32x4 a = *(const f32x4*)sp, c4 = *(const f32x4*)(sp + 4);
#pragma unroll
                for (int u = 0; u < 8; ++u) {
                    const int d = dg * 8 + u;
                    const float x = u < 4 ? a[u] : c4[u - 4];
                    *(unsigned short*)((char*)tiles + 65536 + qc * 16384 + d * 64
                                       + ((jj * 2) ^ ((d & 3) << 4))) = f2bf(x);
                }
            }
        }
        __syncthreads();

        // ---- swapped QK^T: sacc[r] = S[j=crow(r,lh)][q=l31] ----
        f32x16 sacc = zero16();
#pragma unroll
        for (int ks = 0; ks < 16; ++ks) {
            u16x8 kf = *(const u16x8*)(kq + ((((ks * 2 + lh) << 4) ^ xk)));
            sacc = MFMA(kf, qf[ks], sacc);
        }

        // ---- hyperbolic logits -> p (per-lane: one q-row) ----
        float pvv[16];
#pragma unroll
        for (int r = 0; r < 16; ++r) {
            const int crow = (r & 3) + 8 * (r >> 2) + 4 * lh;
            const float k2j = k2sh[qt * Q4 + jb0 + crow];
            const float t = fmaf(-2.f, sacc[r], k2j);                 // k2 - 2S
            const float arg = fmaxf(fmaf(cfr, t, base1), 1.f + 1e-6f);
            const float y = arg + hw_sqrt(fmaf(arg, arg, -1.f));      // e^{arccosh}
            const float p = hw_exp2(hw_log2(y) * -0.0625f);           // y^(-1/16)
            lsum += p;
            pvv[r] = p;
        }

        // ---- in-register P transpose: lane gets A-frag rows (q=l31) ----
        unsigned A_ = cvtpk(pvv[0], pvv[1]),   C_ = cvtpk(pvv[2], pvv[3]);
        unsigned Bv = cvtpk(pvv[4], pvv[5]),   D_ = cvtpk(pvv[6], pvv[7]);
        unsigned E_ = cvtpk(pvv[8], pvv[9]),   G_ = cvtpk(pvv[10], pvv[11]);
        unsigned F_ = cvtpk(pvv[12], pvv[13]), H_ = cvtpk(pvv[14], pvv[15]);
        xswap(A_, Bv, lh); xswap(C_, D_, lh);
        xswap(E_, F_, lh); xswap(G_, H_, lh);
        const u16x8 pa0 = __builtin_bit_cast(u16x8, (u32x4){A_, C_, Bv, D_});
        const u16x8 pa1 = __builtin_bit_cast(u16x8, (u32x4){E_, G_, F_, H_});

        // ---- PV: O += P * V ----
#pragma unroll
        for (int db = 0; db < 8; ++db) {
            u16x8 vf0 = *(const u16x8*)(vq + db * 2048 + ((lh << 4) ^ xv));
            oacc[db] = MFMA(pa0, vf0, oacc[db]);
            u16x8 vf1 = *(const u16x8*)(vq + db * 2048 + (((2 + lh) << 4) ^ xv));
            oacc[db] = MFMA(pa1, vf1, oacc[db]);
        }
    }

    // ---- epilogue: combine 4 KV-quarter partials ----
    lsum += __shfl_xor(lsum, 32, 64);  // join lh halves: total per q=l31 (this qt)
    __syncthreads();                    // all LDS tile reads done
    if (lh == 0) lsumBuf[qt][qg][l31] = lsum;
    float* sf = (float*)tiles;  // 4 slots x 32q x 256d fp32 = 128KB
    if (qt >= 2) {
        const int slot = (qt - 2) * 2 + qg;
#pragma unroll
        for (int db = 0; db < 8; ++db)
#pragma unroll
            for (int r = 0; r < 16; ++r) {
                const int crow = (r & 3) + 8 * (r >> 2) + 4 * lh;
                sf[slot * 8192 + crow * 256 + db * 32 + l31] = oacc[db][r];
            }
    }
    __syncthreads();
    if (qt <= 1) {
        const int slot = qt * 2 + qg;
#pragma unroll
        for (int db = 0; db < 8; ++db)
#pragma unroll
            for (int r = 0; r < 16; ++r) {
                const int crow = (r & 3) + 8 * (r >> 2) + 4 * lh;
                oacc[db][r] += sf[slot * 8192 + crow * 256 + db * 32 + l31];
            }
    }
    __syncthreads();
    if (qt == 1) {
#pragma unroll
        for (int db = 0; db < 8; ++db)
#pragma unroll
            for (int r = 0; r < 16; ++r) {
                const int crow = (r & 3) + 8 * (r >> 2) + 4 * lh;
                sf[qg * 8192 + crow * 256 + db * 32 + l31] = oacc[db][r];
            }
    }
    __syncthreads();
    if (qt == 0) {
        float rdn[16];
#pragma unroll
        for (int r = 0; r < 16; ++r) {
            const int crow = (r & 3) + 8 * (r >> 2) + 4 * lh;
            rdn[r] = 1.0f / (lsumBuf[0][qg][crow] + lsumBuf[1][qg][crow] +
                             lsumBuf[2][qg][crow] + lsumBuf[3][qg][crow]);
        }
#pragma unroll
        for (int db = 0; db < 8; ++db)
#pragma unroll
            for (int r = 0; r < 16; ++r) {
                const int crow = (r & 3) + 8 * (r >> 2) + 4 * lh;
                const float o = oacc[db][r] + sf[qg * 8192 + crow * 256 + db * 32 + l31];
                out[(size_t)(b * S_LEN + qr0 + crow) * D_DIM + db * 32 + l31] = o * rdn[r];
            }
    }
}

// ================= launcher =================
extern "C" void kernel_launch(void* const* d_in, const int* in_sizes, int n_in,
                              void* d_out, int out_size, void* d_ws, size_t ws_size,
                              hipStream_t stream) {
    const float* Q = (const float*)d_in[0];
    const float* K = (const float*)d_in[1];
    const float* V = (const float*)d_in[2];
    const float* cp = (const float*)d_in[3];
    float* out = (float*)d_out;
    (void)in_sizes; (void)n_in; (void)out_size;

    const size_t BS = (size_t)B_N * S_LEN;
    float* q2g = (float*)d_ws;
    float* k2g = q2g + BS;
    float* cfg = k2g + BS;
    unsigned short* Kb = (unsigned short*)(cfg + BS);
    unsigned short* VTg = Kb + BS * D_DIM;
    const size_t need_full = 3 * BS * 4 + 2 * BS * D_DIM * 2;  // ~17 MB

    prep_rows<<<(B_N * S_LEN) / 64, 256, 0, stream>>>(Q, K, cp, q2g, k2g, cfg);

    if (ws_size >= need_full) {
        cvt_bf16<<<(int)((BS * D_DIM / 8) / 256), 256, 0, stream>>>(K, Kb);
        transp_v<<<B_N * (S_LEN / 64) * (D_DIM / 64), 256, 0, stream>>>(V, VTg);
        hyp_attn<1><<<256, 512, 0, stream>>>(Q, K, V, Kb, VTg, q2g, k2g, cfg, out);
    } else {
        hyp_attn<0><<<256, 512, 0, stream>>>(Q, K, V, Kb, VTg, q2g, k2g, cfg, out);
    }
}